// Round 1
// baseline (1452.079 us; speedup 1.0000x reference)
//
#include <hip/hip_runtime.h>

typedef unsigned short u16;
typedef unsigned long long u64;
typedef __bf16 bf16x8 __attribute__((ext_vector_type(8)));
typedef float f32x4 __attribute__((ext_vector_type(4)));

#define T_STEPS 128
#define NB 256
#define HDIM 512
#define DIN_ 255
#define PACK_ 517
#define TN 32768  // T_STEPS*NB

__device__ __forceinline__ float b2f(u16 u) {
    union { unsigned int i; float f; } v; v.i = ((unsigned int)u) << 16; return v.f;
}
__device__ __forceinline__ u16 f2b(float f) {
    union { float f; unsigned int i; } v; v.f = f;
    unsigned int r = v.i + 0x7FFFu + ((v.i >> 16) & 1u);
    return (u16)(r >> 16);
}
__device__ __forceinline__ float sigm(float x) { return 1.f / (1.f + __expf(-x)); }
__device__ __forceinline__ float ftanh(float x) { return 2.f * sigm(2.f * x) - 1.f; }

// 16B L2-bypass load/store (device-coherent: data lands in / is read from L3/MALL,
// never a possibly-stale per-XCD L2). vmcnt tracked manually via the WAIT macros.
__device__ __forceinline__ bf16x8 ldx4_bypass(const u16* p) {
    f32x4 t;
    asm volatile("global_load_dwordx4 %0, %1, off sc0 sc1"
                 : "=v"(t) : "v"(p) : "memory");
    union { f32x4 f; bf16x8 b; } u; u.f = t; return u.b;
}
__device__ __forceinline__ void stx4_bypass(u16* p, bf16x8 v) {
    union { bf16x8 b; f32x4 f; } u; u.b = v;
    asm volatile("global_store_dwordx4 %0, %1, off sc0 sc1"
                 :: "v"(p), "v"(u.f) : "memory");
}
#define WAIT_VMCNT(N) asm volatile("s_waitcnt vmcnt(" #N ")" ::: "memory")
#define WAIT_LGKM0    asm volatile("s_waitcnt lgkmcnt(0)" ::: "memory")

// C[M x N] = act(A @ B^T + bias); B panel (64 x K) staged in LDS fragment-major,
// reused across MT m-tiles. grid (N/64, M/(64*MT)), block 256.
template<int DO_TANH, int K, int MT>
__global__ __launch_bounds__(256) void gemm_bt(const u16* __restrict__ A,
                                               const u16* __restrict__ B,
                                               const float* __restrict__ bias,
                                               u16* __restrict__ C, int N) {
    __shared__ u16 lds[64 * K];  // frag(row,kq) at u16 idx (kq*64+row)*8
    int n0 = blockIdx.x * 64;
    int w = threadIdx.x >> 6, l = threadIdx.x & 63;
    int la = l & 15, lb = l >> 4;
    for (int idx = threadIdx.x; idx < 8 * K; idx += 256) {  // 64*K/8 chunks of 16B
        int kq = idx >> 6, row = idx & 63;
        *(bf16x8*)(lds + (size_t)idx * 8) =
            *(const bf16x8*)(B + (size_t)(n0 + row) * K + kq * 8);
    }
    __syncthreads();
    const u16* bq[4];
    #pragma unroll
    for (int c = 0; c < 4; ++c) bq[c] = lds + ((size_t)lb * 64 + 16 * c + la) * 8;

    for (int mt = 0; mt < MT; ++mt) {
        int m0 = (blockIdx.y * MT + mt) * 64;
        int mw = m0 + 16 * w;
        const u16* Ap = A + (size_t)(mw + la) * K + 8 * lb;
        f32x4 acc[4] = {};
        #pragma unroll
        for (int k0 = 0; k0 < K; k0 += 32) {
            bf16x8 a = *(const bf16x8*)(Ap + k0);
            #pragma unroll
            for (int c = 0; c < 4; ++c)
                acc[c] = __builtin_amdgcn_mfma_f32_16x16x32_bf16(
                    a, *(const bf16x8*)(bq[c] + (size_t)k0 * 64), acc[c], 0, 0, 0);
        }
        #pragma unroll
        for (int c = 0; c < 4; ++c) {
            int n = n0 + 16 * c + la;
            float bv = bias[n];
            #pragma unroll
            for (int r = 0; r < 4; ++r) {
                int m = mw + 4 * lb + r;
                float v = acc[c][r] + bv;
                if (DO_TANH) v = ftanh(v);
                C[(size_t)m * N + n] = f2b(v);
            }
        }
    }
}

// Persistent GRU recurrence, 64 WGs (4 batch groups x 16 output-slice WGs).
// Sync redesign vs previous version:
//   - per-WAVE flags (64 increments/step/group), NO __syncthreads in the loop;
//     each wave drains only its own stores (asm vmcnt(0)) before flagging.
//   - h_new packed to 16B chunks through a per-wave LDS bounce -> one
//     global_store_dwordx4 sc0 sc1 per lane (256 txns/WG/step, was 1024).
//   - h[t-1] loaded as 16 global_load_dwordx4 sc0 sc1 per thread with a counted
//     vmcnt(8) so MFMA kk=0..7 overlaps the tail loads (vmcnt is in-order, so
//     the counted wait is safe even with compiler loads ahead in the queue).
//   - fp32 out stores moved AFTER the flag: off the inter-WG critical path,
//     they complete in the shadow of the next poll wait.
__global__ __launch_bounds__(256, 1) void gru_persist(
    const u16* __restrict__ h0b, const float* __restrict__ hx,
    const u16* __restrict__ whh_b, const float* __restrict__ bhh,
    const u16* __restrict__ gi_b, float* __restrict__ out,
    u16* __restrict__ hs_b, unsigned int* __restrict__ bar) {
    extern __shared__ u16 lds[];  // 98304 B weights + 4096 B pack = 102400 B
    const int tid = threadIdx.x;
    const int b = blockIdx.x >> 4, ksl = blockIdx.x & 15;
    const int ks = ksl * 32, m0 = b * 64;
    const int w = tid >> 6, l = tid & 63;
    const int la = l & 15, lb = l >> 4;
    const int mw = m0 + 16 * w;

    // stage Whh slice -> LDS fragment-major: frag(row,kq) at u16 idx (kq*96+row)*8
    for (int idx = tid; idx < 6144; idx += 256) {
        int kq = idx / 96, row = idx - kq * 96;
        int g = row >> 5, rr = row & 31;
        *(bf16x8*)(lds + (size_t)idx * 8) =
            *(const bf16x8*)(whh_b + (size_t)(g * HDIM + ks + rr) * HDIM + kq * 8);
    }
    const u16* bq[6];
    #pragma unroll
    for (int c = 0; c < 6; ++c) {
        int lr = (c >> 1) * 32 + (c & 1) * 16 + la;
        bq[c] = lds + (size_t)(lb * 96 + lr) * 8;
    }
    float bh[3][2];
    #pragma unroll
    for (int g = 0; g < 3; ++g)
        #pragma unroll
        for (int cc = 0; cc < 2; ++cc)
            bh[g][cc] = bhh[g * HDIM + ks + 16 * cc + la];
    float hp[2][4];
    #pragma unroll
    for (int cc = 0; cc < 2; ++cc)
        #pragma unroll
        for (int r = 0; r < 4; ++r)
            hp[cc][r] = hx[(size_t)(mw + 4 * lb + r) * PACK_ + 4 + ks + 16 * cc + la];

    // per-wave 16x32 u16 pack buffer (intra-wave exchange only -> no barrier)
    u16* packbuf = lds + 49152 + w * 512;

    __syncthreads();
    unsigned int* mybar = bar + b * 64;

    for (int t = 0; t < T_STEPS; ++t) {
        const u16* gi_t = gi_b + (size_t)t * NB * 3 * HDIM;

        // gi prefetch (no cross-WG dependency; in flight during the poll wait)
        u16 giv[3][2][4];
        #pragma unroll
        for (int r = 0; r < 4; ++r) {
            const u16* gp = gi_t + (size_t)(mw + 4 * lb + r) * 1536 + ks + la;
            #pragma unroll
            for (int g = 0; g < 3; ++g)
                #pragma unroll
                for (int cc = 0; cc < 2; ++cc)
                    giv[g][cc][r] = gp[g * HDIM + 16 * cc];
        }

        // wait for h[t-1]: 64 wave-flags per group per step.
        // poll-exit drains vmcnt (compiler waits for the loaded value),
        // so only our asm loads are outstanding afterwards.
        if (t > 0) {
            unsigned tgt = 64u * (unsigned)t;
            while (__hip_atomic_load(mybar, __ATOMIC_RELAXED,
                                     __HIP_MEMORY_SCOPE_AGENT) < tgt)
                __builtin_amdgcn_s_sleep(1);
        }

        // A-fragments: 16B L2-bypass loads
        const u16* Ap = (t ? hs_b + (size_t)(t - 1) * NB * HDIM : h0b)
                        + (size_t)(mw + la) * HDIM + 8 * lb;
        bf16x8 a[16];
        #pragma unroll
        for (int kk = 0; kk < 16; ++kk) a[kk] = ldx4_bypass(Ap + 32 * kk);

        f32x4 acc[6] = {};
        WAIT_VMCNT(8);                       // kk 0..7 landed (in-order count)
        __builtin_amdgcn_sched_barrier(0);   // rule #18: keep MFMA below the wait
        #pragma unroll
        for (int kk = 0; kk < 8; ++kk) {
            #pragma unroll
            for (int c = 0; c < 6; ++c)
                acc[c] = __builtin_amdgcn_mfma_f32_16x16x32_bf16(
                    a[kk], *(const bf16x8*)(bq[c] + (size_t)kk * 3072), acc[c], 0, 0, 0);
        }
        WAIT_VMCNT(0);                       // kk 8..15 landed
        __builtin_amdgcn_sched_barrier(0);
        #pragma unroll
        for (int kk = 8; kk < 16; ++kk) {
            #pragma unroll
            for (int c = 0; c < 6; ++c)
                acc[c] = __builtin_amdgcn_mfma_f32_16x16x32_bf16(
                    a[kk], *(const bf16x8*)(bq[c] + (size_t)kk * 3072), acc[c], 0, 0, 0);
        }

        // epilogue: gate math (fp32 state kept in registers)
        float hnewv[2][4];
        #pragma unroll
        for (int cc = 0; cc < 2; ++cc) {
            #pragma unroll
            for (int r = 0; r < 4; ++r) {
                float hr = acc[0 + cc][r] + bh[0][cc];
                float hz = acc[2 + cc][r] + bh[1][cc];
                float hn = acc[4 + cc][r] + bh[2][cc];
                float rr = sigm(b2f(giv[0][cc][r]) + hr);
                float zz = sigm(b2f(giv[1][cc][r]) + hz);
                float nn = ftanh(b2f(giv[2][cc][r]) + rr * hn);
                float hnew = (1.f - zz) * nn + zz * hp[cc][r];
                hp[cc][r] = hnew;
                hnewv[cc][r] = hnew;
            }
        }

        // pack h_new (bf16) into per-wave LDS tile [16 rows][32 cols]
        #pragma unroll
        for (int cc = 0; cc < 2; ++cc) {
            #pragma unroll
            for (int r = 0; r < 4; ++r) {
                float nbv = __shfl_xor(hnewv[cc][r], 1, 64);
                if (!(la & 1)) {
                    unsigned pk = (unsigned)f2b(hnewv[cc][r]) |
                                  ((unsigned)f2b(nbv) << 16);
                    *(unsigned*)(packbuf + (4 * lb + r) * 32 + 16 * cc + la) = pk;
                }
            }
        }
        WAIT_LGKM0;
        __builtin_amdgcn_sched_barrier(0);
        // one 16B write-through store per lane: row = l>>2, 8-col chunk = l&3
        bf16x8 hv = *(const bf16x8*)(packbuf + (l >> 2) * 32 + 8 * (l & 3));
        u16* hs_t = hs_b + (size_t)t * NB * HDIM;
        stx4_bypass(hs_t + (size_t)(m0 + 16 * w + (l >> 2)) * HDIM + ks + 8 * (l & 3), hv);

        // drain OUR stores only, then flag (per wave). No __syncthreads.
        WAIT_VMCNT(0);
        if (t < T_STEPS - 1 && l == 0)
            __hip_atomic_fetch_add(mybar, 1u, __ATOMIC_RELAXED,
                                   __HIP_MEMORY_SCOPE_AGENT);

        // fp32 h into packed out — AFTER the flag, off the critical path
        float* out_t = out + (size_t)t * NB * PACK_;
        #pragma unroll
        for (int cc = 0; cc < 2; ++cc)
            #pragma unroll
            for (int r = 0; r < 4; ++r)
                out_t[(size_t)(mw + 4 * lb + r) * PACK_ + 4 + ks + 16 * cc + la] =
                    hnewv[cc][r];
    }
}

// one wave per row: out[row*517+off] = dot(X[row,:512], W[:512]) + b[0]
__global__ __launch_bounds__(256) void head_dot(const u16* __restrict__ X,
                                                const u16* __restrict__ W,
                                                const float* __restrict__ b,
                                                float* __restrict__ out, int off) {
    int wid = (int)((blockIdx.x * blockDim.x + threadIdx.x) >> 6);
    int l = threadIdx.x & 63;
    if (wid >= TN) return;
    bf16x8 xv = *(const bf16x8*)(X + (size_t)wid * HDIM + 8 * l);
    bf16x8 wv = *(const bf16x8*)(W + 8 * l);
    float s = 0.f;
    #pragma unroll
    for (int j = 0; j < 8; ++j) s += (float)xv[j] * (float)wv[j];
    #pragma unroll
    for (int d = 32; d; d >>= 1) s += __shfl_down(s, d, 64);
    if (l == 0) out[(size_t)wid * PACK_ + off] = s + b[0];
}

__global__ void prep_w(const float* __restrict__ Wih, const float* __restrict__ Whh,
                       const float* __restrict__ Wa0, const float* __restrict__ Wa1,
                       const float* __restrict__ Wloc, const float* __restrict__ Wc0,
                       const float* __restrict__ Wc1, const float* __restrict__ Wv,
                       const float* __restrict__ hx,
                       u16* Wih_b, u16* Whh_b, u16* Wa0_b, u16* Wa1_b,
                       u16* Wloc_b, u16* Wc0_b, u16* Wc1_b, u16* Wv_b,
                       float* h0f, u16* h0b) {
    int i = blockIdx.x * 256 + threadIdx.x;
    if (i < 1536 * 256) { int r = i >> 8, c = i & 255;
        Wih_b[i] = (c < DIN_) ? f2b(Wih[r * DIN_ + c]) : (u16)0; return; }
    i -= 1536 * 256;
    if (i < 1536 * 512) { Whh_b[i] = f2b(Whh[i]); return; } i -= 1536 * 512;
    if (i < 512 * 512) { Wa0_b[i] = f2b(Wa0[i]); return; } i -= 512 * 512;
    if (i < 512 * 512) { Wa1_b[i] = f2b(Wa1[i]); return; } i -= 512 * 512;
    if (i < 512 * 512) { Wc0_b[i] = f2b(Wc0[i]); return; } i -= 512 * 512;
    if (i < 512 * 512) { Wc1_b[i] = f2b(Wc1[i]); return; } i -= 512 * 512;
    if (i < 512) { Wloc_b[i] = f2b(Wloc[i]); return; } i -= 512;
    if (i < 512) { Wv_b[i] = f2b(Wv[i]); return; } i -= 512;
    if (i < NB * HDIM) { int n = i >> 9, k = i & 511;
        float v = hx[n * PACK_ + 4 + k]; h0f[i] = v; h0b[i] = f2b(v); return; }
}

// vectorized: each thread converts 8 contiguous f32 -> bf16x8 (zeroing d=255)
__global__ void prep_obs(const float* __restrict__ in, u16* __restrict__ obs) {
    int idx = blockIdx.x * 256 + threadIdx.x;
    if (idx >= TN * 32) return;
    int m = idx >> 5, j = idx & 31;
    const float* src = in + (size_t)m * 256 + 8 * j;
    union { u16 s[8]; uint4 u; } t;
    #pragma unroll
    for (int q = 0; q < 8; ++q) t.s[q] = f2b(src[q]);
    if (j == 31) t.s[7] = 0;  // d=255 is the actions column
    *(uint4*)(obs + (size_t)m * 256 + 8 * j) = t.u;
}

__global__ void finalize_out(const float* __restrict__ in, const float* __restrict__ eps,
                             const float* __restrict__ hx, const float* __restrict__ logstd,
                             float* __restrict__ out) {
    int m = blockIdx.x * 256 + threadIdx.x;
    if (m >= TN) return;
    int n = m & (NB - 1);
    float scale = __expf(logstd[0]);
    float loc = out[(size_t)m * PACK_ + 1];
    float act = in[(size_t)m * 256 + DIN_];
    float a = (act < 0.f) ? (loc + scale * eps[m]) : act;
    out[(size_t)m * PACK_ + 0] = a;
    out[(size_t)m * PACK_ + 2] = scale;
    out[(size_t)m * PACK_ + PACK_ - 1] = hx[n * PACK_ + PACK_ - 1];
}

__global__ void tail_copy(float* __restrict__ out) {
    int i = blockIdx.x * 256 + threadIdx.x;
    if (i >= NB * PACK_) return;
    out[(size_t)T_STEPS * NB * PACK_ + i] = out[(size_t)(T_STEPS - 1) * NB * PACK_ + i];
}

extern "C" void kernel_launch(void* const* d_in, const int* in_sizes, int n_in,
                              void* d_out, int out_size, void* d_ws, size_t ws_size,
                              hipStream_t stream) {
    const float* inputs = (const float*)d_in[0];
    const float* hx     = (const float*)d_in[1];
    const float* eps    = (const float*)d_in[2];
    const float* Wih    = (const float*)d_in[3];
    const float* Whh    = (const float*)d_in[4];
    const float* bih    = (const float*)d_in[5];
    const float* bhh    = (const float*)d_in[6];
    const float* Wa0    = (const float*)d_in[7];
    const float* ba0    = (const float*)d_in[8];
    const float* Wa1    = (const float*)d_in[9];
    const float* ba1    = (const float*)d_in[10];
    const float* Wloc   = (const float*)d_in[11];
    const float* bloc   = (const float*)d_in[12];
    const float* logstd = (const float*)d_in[13];
    const float* Wc0    = (const float*)d_in[14];
    const float* bc0    = (const float*)d_in[15];
    const float* Wc1    = (const float*)d_in[16];
    const float* bc1    = (const float*)d_in[17];
    const float* Wv     = (const float*)d_in[18];
    const float* bv     = (const float*)d_in[19];
    float* out = (float*)d_out;
    char* ws = (char*)d_ws;

    const size_t o_gi   = 0;                       // 100,663,296
    const size_t o_buf0 = 0;                       // alias (gi dead before MLPs)
    const size_t o_buf1 = 33554432;
    const size_t o_hs   = 100663296;               // 33,554,432
    const size_t o_obs  = o_hs + 33554432;         // 16,777,216
    const size_t o_whh  = o_obs + 16777216;        // 1,572,864
    const size_t o_wih  = o_whh + 1572864;         // 786,432
    const size_t o_wa0  = o_wih + 786432;
    const size_t o_wa1  = o_wa0 + 524288;
    const size_t o_wc0  = o_wa1 + 524288;
    const size_t o_wc1  = o_wc0 + 524288;
    const size_t o_wloc = o_wc1 + 524288;
    const size_t o_wv   = o_wloc + 1024;
    const size_t o_h0f  = o_wv + 1024;
    const size_t o_h0b  = o_h0f + 524288;
    const size_t o_bar  = o_h0b + 262144;          // 4 group counters, 256B apart
    const size_t NEED   = o_bar + 4096;
    if (ws_size < NEED) return;

    u16*   gi_b   = (u16*)(ws + o_gi);
    u16*   buf0   = (u16*)(ws + o_buf0);
    u16*   buf1   = (u16*)(ws + o_buf1);
    u16*   hs_b   = (u16*)(ws + o_hs);
    u16*   obs_b  = (u16*)(ws + o_obs);
    u16*   whh_b  = (u16*)(ws + o_whh);
    u16*   wih_b  = (u16*)(ws + o_wih);
    u16*   wa0_b  = (u16*)(ws + o_wa0);
    u16*   wa1_b  = (u16*)(ws + o_wa1);
    u16*   wc0_b  = (u16*)(ws + o_wc0);
    u16*   wc1_b  = (u16*)(ws + o_wc1);
    u16*   wloc_b = (u16*)(ws + o_wloc);
    u16*   wv_b   = (u16*)(ws + o_wv);
    float* h0f    = (float*)(ws + o_h0f);
    u16*   h0b    = (u16*)(ws + o_h0b);
    unsigned int* bar = (unsigned int*)(ws + o_bar);

    static bool attr_set = false;
    if (!attr_set) {  // host-side attribute config, idempotent
        hipFuncSetAttribute((const void*)gru_persist,
                            hipFuncAttributeMaxDynamicSharedMemorySize, 102400);
        attr_set = true;
    }

    hipMemsetAsync(bar, 0, 4096, stream);  // deterministic barrier state each call

    prep_w<<<9220, 256, 0, stream>>>(Wih, Whh, Wa0, Wa1, Wloc, Wc0, Wc1, Wv, hx,
                                     wih_b, whh_b, wa0_b, wa1_b, wloc_b, wc0_b, wc1_b, wv_b,
                                     h0f, h0b);
    prep_obs<<<4096, 256, 0, stream>>>(inputs, obs_b);

    // gi = obs_pad @ Wih_pad^T + bih   (M=32768, N=1536, K=256)
    gemm_bt<0, 256, 8><<<dim3(24, 64), 256, 0, stream>>>(obs_b, wih_b, bih, gi_b, 1536);

    // persistent recurrence: 64 WGs, 102400 B dynamic LDS each
    gru_persist<<<64, 256, 102400, stream>>>(h0b, hx, whh_b, bhh, gi_b, out, hs_b, bar);

    // actor MLP
    gemm_bt<1, 512, 8><<<dim3(8, 64), 256, 0, stream>>>(hs_b, wa0_b, ba0, buf0, 512);
    gemm_bt<1, 512, 8><<<dim3(8, 64), 256, 0, stream>>>(buf0, wa1_b, ba1, buf1, 512);
    head_dot<<<8192, 256, 0, stream>>>(buf1, wloc_b, bloc, out, 1);
    // critic MLP
    gemm_bt<1, 512, 8><<<dim3(8, 64), 256, 0, stream>>>(hs_b, wc0_b, bc0, buf0, 512);
    gemm_bt<1, 512, 8><<<dim3(8, 64), 256, 0, stream>>>(buf0, wc1_b, bc1, buf1, 512);
    head_dot<<<8192, 256, 0, stream>>>(buf1, wv_b, bv, out, 3);

    finalize_out<<<128, 256, 0, stream>>>(inputs, eps, hx, logstd, out);
    tail_copy<<<518, 256, 0, stream>>>(out);
}